// Round 5
// baseline (463.025 us; speedup 1.0000x reference)
//
#include <hip/hip_runtime.h>
#include <math.h>

#define NW 100000
#define NS 10000
#define NE 800000
#define DIM 256
#define NH 4
#define DFF 512
#define NEG_SLOPE 0.2f
#define CAP 64   // bucket capacity; deg ~ Poisson(8), P(>64) ~ 0

#define NZB 391          // ceil(NW/256) zero blocks
#define FG_B 625         // feat_gemm blocks (NS/16)
#define SC_B 3125        // scatter blocks (NE/256)

typedef __attribute__((ext_vector_type(8))) short bf16x8;
typedef __attribute__((ext_vector_type(8))) unsigned short ushortx8;
typedef __attribute__((ext_vector_type(16))) float floatx16;

// ---------------- helpers ----------------
__device__ __forceinline__ unsigned short f2bf(float f) {  // RNE fp32->bf16
    unsigned int u = __float_as_uint(f);
    unsigned int r = (u + 0x7fffu + ((u >> 16) & 1u)) >> 16;
    return (unsigned short)r;
}
__device__ __forceinline__ float bf2f(unsigned short u) {
    return __uint_as_float(((unsigned int)u) << 16);
}
__device__ __forceinline__ void gload_lds16(const void* g, void* l) {
    __builtin_amdgcn_global_load_lds(
        (const __attribute__((address_space(1))) unsigned int*)g,
        (__attribute__((address_space(3))) unsigned int*)l, 16, 0, 0);
}
// packs (lo,hi) -> [15:0]=bf16(lo), [31:16]=bf16(hi), RNE
__device__ __forceinline__ unsigned int cvt_pk_bf16(float lo, float hi) {
    unsigned int d;
    asm("v_cvt_pk_bf16_f32 %0, %1, %2" : "=v"(d) : "v"(lo), "v"(hi));
    return d;
}
// a'[i+32] = b[i]; b'[i] = a[i+32]
__device__ __forceinline__ void permlane32_swap(unsigned int& a, unsigned int& b) {
    asm("v_permlane32_swap_b32 %0, %1" : "+v"(a), "+v"(b));
}

// ---------------- merged prep kernel ----------------
// blocks: [0,391) zero_count | [391,392) compute_C (C_dst) |
//         [392,1160) prep_weights | [1160,1785) feat_gemm (+el fused).
__global__ __launch_bounds__(256) void prep_all(
    const float* __restrict__ sent, const float* __restrict__ W_src,
    const float* __restrict__ attn_l, const float* __restrict__ W_dst,
    const float* __restrict__ attn_r, const float* __restrict__ w1,
    const float* __restrict__ w2,
    float* __restrict__ C_dst,
    unsigned short* __restrict__ w1p, unsigned short* __restrict__ w2p,
    int* __restrict__ count, unsigned short* __restrict__ feat16,
    float* __restrict__ el)
{
    int b = blockIdx.x, t = threadIdx.x;
    if (b < NZB) {
        int i = b * 256 + t;
        if (i < NW) count[i] = 0;
    } else if (b < NZB + 1) {
        // C_dst[k,h] = sum_d W_dst[k, h*64+d] * attn_r[h,d]
        int k = t;
#pragma unroll
        for (int h = 0; h < NH; h++) {
            const float4* Wv = (const float4*)(W_dst + (size_t)k * DIM + h * 64);
            const float4* Av = (const float4*)(attn_r + h * 64);
            float s = 0.f;
#pragma unroll
            for (int d = 0; d < 16; d++) {
                float4 w = Wv[d], a = Av[d];
                s += w.x * a.x + w.y * a.y + w.z * a.z + w.w * a.w;
            }
            C_dst[k * NH + h] = s;
        }
    } else if (b < NZB + 1 + DFF + 256) {
        // fragment-packed weights, octet layout [k>>3][n][k&7]
        int bb = b - (NZB + 1);
        if (bb < DFF) {
            int n = bb, k = t;   // w1[k][n]
            w1p[((size_t)(k >> 3) * 512 + n) * 8 + (k & 7)] = f2bf(w1[(size_t)k * DFF + n]);
        } else {
            int c = bb - DFF;    // w2[k2][c]
#pragma unroll
            for (int kk = 0; kk < 2; kk++) {
                int k2 = t + kk * 256;
                w2p[((size_t)(k2 >> 3) * 256 + c) * 8 + (k2 & 7)] = f2bf(w2[(size_t)k2 * 256 + c]);
            }
        }
    } else {
        // feat16 = bf16(sent @ W_src); el fused from register accumulators
        __shared__ float a[16][DIM];
        int rg = t >> 6;
        int lane = t & 63;
        int c0 = lane * 4;
        size_t row0 = (size_t)(b - (NZB + 1 + DFF + 256)) * 16;
#pragma unroll 4
        for (int i = 0; i < 16; i++) a[i][t] = sent[(row0 + i) * DIM + t];
        __syncthreads();
        float acc[4][4] = {};
        for (int kk = 0; kk < DIM; kk += 4) {
            float af[4][4];
#pragma unroll
            for (int i = 0; i < 4; i++) {
                float4 v = *(const float4*)&a[rg * 4 + i][kk];
                af[i][0] = v.x; af[i][1] = v.y; af[i][2] = v.z; af[i][3] = v.w;
            }
            float wf[4][4];
#pragma unroll
            for (int j2 = 0; j2 < 4; j2++) {
                float4 v = *(const float4*)&W_src[(size_t)(kk + j2) * DIM + c0];
                wf[j2][0] = v.x; wf[j2][1] = v.y; wf[j2][2] = v.z; wf[j2][3] = v.w;
            }
#pragma unroll
            for (int i = 0; i < 4; i++)
#pragma unroll
                for (int j2 = 0; j2 < 4; j2++)
#pragma unroll
                    for (int j = 0; j < 4; j++)
                        acc[i][j] = fmaf(af[i][j2], wf[j2][j], acc[i][j]);
        }
#pragma unroll
        for (int i = 0; i < 4; i++) {
            ushort4 p;
            p.x = f2bf(acc[i][0]); p.y = f2bf(acc[i][1]);
            p.z = f2bf(acc[i][2]); p.w = f2bf(acc[i][3]);
            *(ushort4*)&feat16[(row0 + rg * 4 + i) * DIM + c0] = p;
        }
        // el[n,h] = sum_d feat[n, h*64+d] * attn_l[h*64+d]; head = lane>>4
        int hh2 = lane >> 4;
        float4 alv = *(const float4*)(attn_l + c0);
#pragma unroll
        for (int i = 0; i < 4; i++) {
            float pel = acc[i][0] * alv.x + acc[i][1] * alv.y
                      + acc[i][2] * alv.z + acc[i][3] * alv.w;
#pragma unroll
            for (int m = 1; m < 16; m <<= 1) pel += __shfl_xor(pel, m, 64);
            if ((lane & 15) == 0)
                el[(row0 + rg * 4 + i) * NH + hh2] = pel;
        }
    }
}

// ---------------- scatter ----------------
__global__ void scatter_edges(const int* __restrict__ src, const int* __restrict__ dst,
                              int* __restrict__ count, unsigned short* __restrict__ bucket) {
    int e = blockIdx.x * 256 + threadIdx.x;
    if (e >= NE) return;
    int w = dst[e];
    int pos = atomicAdd(&count[w], 1);
    if (pos < CAP) bucket[(size_t)w * CAP + pos] = (unsigned short)src[e];
}

// ---------------- GAT: 2 nodes per wave, h -> bf16 ----------------
// hbf row n INTERLEAVED into d_out: bytes [1024n+512, 1024n+1024).
// Gather loop unrolled 8/4-wide: group loads issued back-to-back so the
// random feat16 row reads overlap (was 1 dependent load per iteration).
__global__ __launch_bounds__(256) void gat_h(
    const int* __restrict__ count, const unsigned short* __restrict__ bucket,
    const float* __restrict__ el, const float* __restrict__ Cdst,
    const unsigned short* __restrict__ feat16, const float* __restrict__ word,
    const float* __restrict__ gat_bias, unsigned short* hb)
{
    __shared__ unsigned short sbuf[8][64];
    __shared__ float abuf[8][4][64];
    int tid = threadIdx.x;
    int lane = tid & 63, wv = tid >> 6;
    int hl = lane & 31, half = lane >> 5;
    int nl = wv * 2 + half;                 // node-local 0..7
    int node = blockIdx.x * 8 + nl;
    int deg = count[node]; if (deg > CAP) deg = CAP;

    const float4* wr = (const float4*)(word + (size_t)node * DIM);
    float4 w0 = wr[hl * 2], w1v = wr[hl * 2 + 1];
    float wcol[8] = {w0.x, w0.y, w0.z, w0.w, w1v.x, w1v.y, w1v.z, w1v.w};

    // er inline: p[h] = sum_k word[k] * Cdst[k][h]
    const float4* Cv = (const float4*)Cdst;
    float p0 = 0.f, p1 = 0.f, p2 = 0.f, p3 = 0.f;
#pragma unroll
    for (int j = 0; j < 8; j++) {
        float4 c = Cv[hl * 8 + j];
        float wj = wcol[j];
        p0 = fmaf(wj, c.x, p0); p1 = fmaf(wj, c.y, p1);
        p2 = fmaf(wj, c.z, p2); p3 = fmaf(wj, c.w, p3);
    }
#pragma unroll
    for (int m = 1; m < 32; m <<= 1) {
        p0 += __shfl_xor(p0, m, 64); p1 += __shfl_xor(p1, m, 64);
        p2 += __shfl_xor(p2, m, 64); p3 += __shfl_xor(p3, m, 64);
    }

    // un-normalized exp scores for slots hl and hl+32 (scores bounded, no max)
    int sa = 0, sb = 0;
    float xa0 = 0.f, xa1 = 0.f, xa2 = 0.f, xa3 = 0.f;
    float xb0 = 0.f, xb1 = 0.f, xb2 = 0.f, xb3 = 0.f;
    if (hl < deg) {
        sa = bucket[(size_t)node * CAP + hl];
        float4 e = ((const float4*)el)[sa];
        float v;
        v = e.x + p0; xa0 = expf(v > 0.f ? v : NEG_SLOPE * v);
        v = e.y + p1; xa1 = expf(v > 0.f ? v : NEG_SLOPE * v);
        v = e.z + p2; xa2 = expf(v > 0.f ? v : NEG_SLOPE * v);
        v = e.w + p3; xa3 = expf(v > 0.f ? v : NEG_SLOPE * v);
    }
    if (hl + 32 < deg) {
        sb = bucket[(size_t)node * CAP + hl + 32];
        float4 e = ((const float4*)el)[sb];
        float v;
        v = e.x + p0; xb0 = expf(v > 0.f ? v : NEG_SLOPE * v);
        v = e.y + p1; xb1 = expf(v > 0.f ? v : NEG_SLOPE * v);
        v = e.z + p2; xb2 = expf(v > 0.f ? v : NEG_SLOPE * v);
        v = e.w + p3; xb3 = expf(v > 0.f ? v : NEG_SLOPE * v);
    }
    float d0 = xa0 + xb0, d1 = xa1 + xb1, d2 = xa2 + xb2, d3 = xa3 + xb3;
#pragma unroll
    for (int m = 1; m < 32; m <<= 1) {
        d0 += __shfl_xor(d0, m, 64); d1 += __shfl_xor(d1, m, 64);
        d2 += __shfl_xor(d2, m, 64); d3 += __shfl_xor(d3, m, 64);
    }
    float i0 = 1.f / d0, i1 = 1.f / d1, i2 = 1.f / d2, i3 = 1.f / d3;
    sbuf[nl][hl] = (unsigned short)sa;
    sbuf[nl][hl + 32] = (unsigned short)sb;
    abuf[nl][0][hl] = xa0 * i0; abuf[nl][0][hl + 32] = xb0 * i0;
    abuf[nl][1][hl] = xa1 * i1; abuf[nl][1][hl + 32] = xb1 * i1;
    abuf[nl][2][hl] = xa2 * i2; abuf[nl][2][hl + 32] = xb2 * i2;
    abuf[nl][3][hl] = xa3 * i3; abuf[nl][3][hl + 32] = xb3 * i3;
    __syncthreads();

    // gather: lane covers 8 cols, head hh = hl>>3; 8/4-wide latency batching
    int hh = hl >> 3;
    float acc[8] = {};
    const unsigned short* fcol = feat16 + hl * 8;
    int i = 0;
    for (; i + 8 <= deg; i += 8) {
        ushortx8 sv = *(const ushortx8*)&sbuf[nl][i];
        float4 a0 = *(const float4*)&abuf[nl][hh][i];
        float4 a1 = *(const float4*)&abuf[nl][hh][i + 4];
        ushortx8 f0 = *(const ushortx8*)&fcol[(size_t)sv[0] * DIM];
        ushortx8 f1 = *(const ushortx8*)&fcol[(size_t)sv[1] * DIM];
        ushortx8 f2 = *(const ushortx8*)&fcol[(size_t)sv[2] * DIM];
        ushortx8 f3 = *(const ushortx8*)&fcol[(size_t)sv[3] * DIM];
        ushortx8 f4 = *(const ushortx8*)&fcol[(size_t)sv[4] * DIM];
        ushortx8 f5 = *(const ushortx8*)&fcol[(size_t)sv[5] * DIM];
        ushortx8 f6 = *(const ushortx8*)&fcol[(size_t)sv[6] * DIM];
        ushortx8 f7 = *(const ushortx8*)&fcol[(size_t)sv[7] * DIM];
#pragma unroll
        for (int j = 0; j < 8; j++) {
            float s = acc[j];
            s = fmaf(a0.x, bf2f(f0[j]), s); s = fmaf(a0.y, bf2f(f1[j]), s);
            s = fmaf(a0.z, bf2f(f2[j]), s); s = fmaf(a0.w, bf2f(f3[j]), s);
            s = fmaf(a1.x, bf2f(f4[j]), s); s = fmaf(a1.y, bf2f(f5[j]), s);
            s = fmaf(a1.z, bf2f(f6[j]), s); s = fmaf(a1.w, bf2f(f7[j]), s);
            acc[j] = s;
        }
    }
    for (; i + 4 <= deg; i += 4) {
        ushort4 sv = *(const ushort4*)&sbuf[nl][i];
        float4 a0 = *(const float4*)&abuf[nl][hh][i];
        ushortx8 f0 = *(const ushortx8*)&fcol[(size_t)sv.x * DIM];
        ushortx8 f1 = *(const ushortx8*)&fcol[(size_t)sv.y * DIM];
        ushortx8 f2 = *(const ushortx8*)&fcol[(size_t)sv.z * DIM];
        ushortx8 f3 = *(const ushortx8*)&fcol[(size_t)sv.w * DIM];
#pragma unroll
        for (int j = 0; j < 8; j++) {
            float s = acc[j];
            s = fmaf(a0.x, bf2f(f0[j]), s); s = fmaf(a0.y, bf2f(f1[j]), s);
            s = fmaf(a0.z, bf2f(f2[j]), s); s = fmaf(a0.w, bf2f(f3[j]), s);
            acc[j] = s;
        }
    }
    for (; i < deg; i++) {
        int si = sbuf[nl][i];
        float aa = abuf[nl][hh][i];
        ushortx8 f = *(const ushortx8*)&fcol[(size_t)si * DIM];
#pragma unroll
        for (int j = 0; j < 8; j++) acc[j] = fmaf(aa, bf2f(f[j]), acc[j]);
    }

    float4 g0 = ((const float4*)gat_bias)[hl * 2], g1 = ((const float4*)gat_bias)[hl * 2 + 1];
    float gb[8] = {g0.x, g0.y, g0.z, g0.w, g1.x, g1.y, g1.z, g1.w};
    ushortx8 o;
#pragma unroll
    for (int j = 0; j < 8; j++) {
        float r = acc[j] + gb[j];
        r = r > 0.f ? r : (expf(r) - 1.f);
        o[j] = f2bf(wcol[j] + r);
    }
    *(ushortx8*)&hb[(size_t)node * 512 + 256 + hl * 8] = o;
}

// ---------------- Fused FFN v3: H in regs, weights LDS-double-buffered ----
// BM=256 rows, 512 threads (8 waves), each wave owns 32 rows x 256 out cols.
// H (32 rows x K=256) loaded ONCE to registers -> GEMM1's B operand free.
// Per 32-hid chunk: W1+W2 slices (32 KB) staged to LDS via global_load_lds,
// double-buffered one chunk ahead.  G1 swapped -> lane=row; bias/relu in regs;
// cvt_pk + permlane32_swap -> G2 A-frags in-register; G2 accumulates 256 cols.
__global__ __launch_bounds__(512, 2) void ffn_fused3(
    const unsigned short* hb,                // = (ushort*)d_out (aliases out!)
    const unsigned short* __restrict__ w1p,
    const float* __restrict__ b1,
    const unsigned short* __restrict__ w2p,
    const float* __restrict__ b2,
    float* out)
{
    __shared__ unsigned short W1s[2][8192];  // 16 KB each
    __shared__ unsigned short W2s[2][8192];
    int tid = threadIdx.x;
    int lane = tid & 63, wv = tid >> 6;
    int l31 = lane & 31, half = lane >> 5;
    int row0 = blockIdx.x * 256;

    int myrow = row0 + wv * 32 + l31;
    if (myrow >= NW) myrow = NW - 1;
    const unsigned short* hrow = hb + (size_t)myrow * 512 + 256 + half * 8;
    bf16x8 hreg[16];
#pragma unroll
    for (int ks = 0; ks < 16; ks++)
        hreg[ks] = *(const bf16x8*)(hrow + ks * 16);

    // stage chunk 0
    {
        if (wv < 4) {
#pragma unroll
            for (int it = 0; it < 4; it++) {
                int q = wv * 4 + it;
                const unsigned short* s =
                    w1p + ((size_t)(q * 2 + (lane >> 5)) * 512 + (lane & 31)) * 8;
                gload_lds16(s, &W1s[0][q * 512]);
            }
        } else {
#pragma unroll
            for (int it = 0; it < 4; it++) {
                int qq = (wv - 4) * 4 + it;
                const unsigned short* s = w2p + ((size_t)qq * 64 + lane) * 8;
                gload_lds16(s, &W2s[0][qq * 512]);
            }
        }
    }

    floatx16 oacc[8];
#pragma unroll
    for (int j = 0; j < 8; j++) oacc[j] = (floatx16)(0.f);
    __syncthreads();

#pragma unroll 2
    for (int hbi = 0; hbi < 16; hbi++) {
        int cur = hbi & 1;
        if (hbi < 15) {
            int c = hbi + 1, nb = cur ^ 1;
            if (wv < 4) {
#pragma unroll
                for (int it = 0; it < 4; it++) {
                    int q = wv * 4 + it;
                    const unsigned short* s =
                        w1p + ((size_t)(q * 2 + (lane >> 5)) * 512 + c * 32 + (lane & 31)) * 8;
                    gload_lds16(s, &W1s[nb][q * 512]);
                }
            } else {
#pragma unroll
                for (int it = 0; it < 4; it++) {
                    int qq = (wv - 4) * 4 + it;
                    const unsigned short* s = w2p + ((size_t)c * 1024 + qq * 64 + lane) * 8;
                    gload_lds16(s, &W2s[nb][qq * 512]);
                }
            }
        }
        const bf16x8* W1v = (const bf16x8*)W1s[cur];
        floatx16 hacc = (floatx16)(0.f);
#pragma unroll
        for (int ks = 0; ks < 16; ks++) {
            bf16x8 afrag = W1v[(ks * 2 + half) * 32 + l31];
            hacc = __builtin_amdgcn_mfma_f32_32x32x16_bf16(afrag, hreg[ks], hacc, 0, 0, 0);
        }
        const float* b1b = b1 + hbi * 32 + 4 * half;
        float4 bb0 = *(const float4*)(b1b + 0);
        float4 bb1 = *(const float4*)(b1b + 8);
        float4 bb2 = *(const float4*)(b1b + 16);
        float4 bb3 = *(const float4*)(b1b + 24);
        float bs[16] = {bb0.x, bb0.y, bb0.z, bb0.w, bb1.x, bb1.y, bb1.z, bb1.w,
                        bb2.x, bb2.y, bb2.z, bb2.w, bb3.x, bb3.y, bb3.z, bb3.w};
        float p[16];
#pragma unroll
        for (int j = 0; j < 16; j++) {
            float v = hacc[j] + bs[j];
            p[j] = v > 0.f ? v : 0.f;
        }
        unsigned int pk0 = cvt_pk_bf16(p[0], p[1]),   pk1 = cvt_pk_bf16(p[2], p[3]);
        unsigned int pk2 = cvt_pk_bf16(p[4], p[5]),   pk3 = cvt_pk_bf16(p[6], p[7]);
        unsigned int pk4 = cvt_pk_bf16(p[8], p[9]),   pk5 = cvt_pk_bf16(p[10], p[11]);
        unsigned int pk6 = cvt_pk_bf16(p[12], p[13]), pk7 = cvt_pk_bf16(p[14], p[15]);
        permlane32_swap(pk0, pk2);
        permlane32_swap(pk1, pk3);
        permlane32_swap(pk4, pk6);
        permlane32_swap(pk5, pk7);
        union { unsigned int u[4]; bf16x8 v; } f0, f1;
        f0.u[0] = pk0; f0.u[1] = pk1; f0.u[2] = pk2; f0.u[3] = pk3;  // hid 0..15
        f1.u[0] = pk4; f1.u[1] = pk5; f1.u[2] = pk6; f1.u[3] = pk7;  // hid 16..31
        const bf16x8* W2v = (const bf16x8*)W2s[cur];
#pragma unroll
        for (int ks2 = 0; ks2 < 2; ks2++) {
            bf16x8 pa = ks2 ? f1.v : f0.v;
#pragma unroll
            for (int ct = 0; ct < 8; ct++) {
                bf16x8 bfr = W2v[(ks2 * 2 + half) * 256 + ct * 32 + l31];
                oacc[ct] = __builtin_amdgcn_mfma_f32_32x32x16_bf16(pa, bfr, oacc[ct], 0, 0, 0);
            }
        }
        if (hbi < 15) __syncthreads();
    }
#pragma unroll
    for (int ct = 0; ct < 8; ct++) {
        int c = ct * 32 + l31;
        float bias = b2[c];
#pragma unroll
        for (int reg = 0; reg < 16; reg++) {
            int rloc = row0 + wv * 32 + (reg & 3) + 8 * (reg >> 2) + 4 * half;
            if (rloc < NW) out[(size_t)rloc * DIM + c] = oacc[ct][reg] + bias;
        }
    }
}

// ---------------- launch ----------------
extern "C" void kernel_launch(void* const* d_in, const int* in_sizes, int n_in,
                              void* d_out, int out_size, void* d_ws, size_t ws_size,
                              hipStream_t stream) {
    const float* word   = (const float*)d_in[0];
    const float* sent   = (const float*)d_in[1];
    const int*   src    = (const int*)d_in[2];
    const int*   dst    = (const int*)d_in[3];
    const float* W_src  = (const float*)d_in[4];
    const float* W_dst  = (const float*)d_in[5];
    const float* attn_l = (const float*)d_in[6];
    const float* attn_r = (const float*)d_in[7];
    const float* gbias  = (const float*)d_in[8];
    const float* w1     = (const float*)d_in[9];
    const float* b1     = (const float*)d_in[10];
    const float* w2     = (const float*)d_in[11];
    const float* b2     = (const float*)d_in[12];
    float* out = (float*)d_out;
    // hbf row n interleaved into d_out bytes [1024n+512, 1024n+1024)
    unsigned short* hb = (unsigned short*)d_out;

    char* wsb = (char*)d_ws;
    unsigned short* w1p = (unsigned short*)wsb;                 // 512*256
    unsigned short* w2p = w1p + (size_t)DFF * 256;              // 256*512
    float* el    = (float*)(w2p + (size_t)256 * DFF);           // NS*4
    float* C_dst = el + (size_t)NS * NH;                        // 256*4
    unsigned short* feat16 = (unsigned short*)(C_dst + DIM * NH);  // NS*256
    int* count = (int*)(feat16 + (size_t)NS * DIM);             // NW
    unsigned short* bucket = (unsigned short*)(count + NW);     // NW*CAP

    hipLaunchKernelGGL(prep_all, dim3(NZB + 1 + DFF + 256 + FG_B), dim3(256), 0, stream,
                       sent, W_src, attn_l, W_dst, attn_r, w1, w2,
                       C_dst, w1p, w2p, count, feat16, el);
    hipLaunchKernelGGL(scatter_edges, dim3(SC_B), dim3(256), 0, stream, src, dst, count, bucket);
    hipLaunchKernelGGL(gat_h, dim3(NW / 8), dim3(256), 0, stream,
                       count, bucket, el, C_dst, feat16, word, gbias, hb);
    hipLaunchKernelGGL(ffn_fused3, dim3(391), dim3(512), 0, stream,
                       hb, w1p, b1, w2p, b2, out);
}

// Round 6
// 438.731 us; speedup vs baseline: 1.0554x; 1.0554x over previous
//
#include <hip/hip_runtime.h>
#include <math.h>

#define NW 100000
#define NS 10000
#define NE 800000
#define DIM 256
#define NH 4
#define DFF 512
#define NEG_SLOPE 0.2f
#define CAP 64   // bucket capacity; deg ~ Poisson(8), P(>64) ~ 0

#define NZB 391          // ceil(NW/256) zero blocks
#define FG_B 625         // feat_gemm blocks (NS/16)
#define SC_B 3125        // scatter blocks (NE/256)

typedef __attribute__((ext_vector_type(8))) short bf16x8;
typedef __attribute__((ext_vector_type(8))) unsigned short ushortx8;
typedef __attribute__((ext_vector_type(16))) float floatx16;

// ---------------- helpers ----------------
__device__ __forceinline__ unsigned short f2bf(float f) {  // RNE fp32->bf16
    unsigned int u = __float_as_uint(f);
    unsigned int r = (u + 0x7fffu + ((u >> 16) & 1u)) >> 16;
    return (unsigned short)r;
}
__device__ __forceinline__ float bf2f(unsigned short u) {
    return __uint_as_float(((unsigned int)u) << 16);
}
__device__ __forceinline__ void gload_lds16(const void* g, void* l) {
    __builtin_amdgcn_global_load_lds(
        (const __attribute__((address_space(1))) unsigned int*)g,
        (__attribute__((address_space(3))) unsigned int*)l, 16, 0, 0);
}
// packs (lo,hi) -> [15:0]=bf16(lo), [31:16]=bf16(hi), RNE
__device__ __forceinline__ unsigned int cvt_pk_bf16(float lo, float hi) {
    unsigned int d;
    asm("v_cvt_pk_bf16_f32 %0, %1, %2" : "=v"(d) : "v"(lo), "v"(hi));
    return d;
}
// a'[i+32] = b[i]; b'[i] = a[i+32]
__device__ __forceinline__ void permlane32_swap(unsigned int& a, unsigned int& b) {
    asm("v_permlane32_swap_b32 %0, %1" : "+v"(a), "+v"(b));
}

// ---------------- merged prep kernel ----------------
// blocks: [0,391) zero_count | [391,392) compute_C (C_dst) |
//         [392,1160) prep_weights | [1160,1785) feat_gemm (+el fused).
__global__ __launch_bounds__(256) void prep_all(
    const float* __restrict__ sent, const float* __restrict__ W_src,
    const float* __restrict__ attn_l, const float* __restrict__ W_dst,
    const float* __restrict__ attn_r, const float* __restrict__ w1,
    const float* __restrict__ w2,
    float* __restrict__ C_dst,
    unsigned short* __restrict__ w1p, unsigned short* __restrict__ w2p,
    int* __restrict__ count, unsigned short* __restrict__ feat16,
    float* __restrict__ el)
{
    int b = blockIdx.x, t = threadIdx.x;
    if (b < NZB) {
        int i = b * 256 + t;
        if (i < NW) count[i] = 0;
    } else if (b < NZB + 1) {
        // C_dst[k,h] = sum_d W_dst[k, h*64+d] * attn_r[h,d]
        int k = t;
#pragma unroll
        for (int h = 0; h < NH; h++) {
            const float4* Wv = (const float4*)(W_dst + (size_t)k * DIM + h * 64);
            const float4* Av = (const float4*)(attn_r + h * 64);
            float s = 0.f;
#pragma unroll
            for (int d = 0; d < 16; d++) {
                float4 w = Wv[d], a = Av[d];
                s += w.x * a.x + w.y * a.y + w.z * a.z + w.w * a.w;
            }
            C_dst[k * NH + h] = s;
        }
    } else if (b < NZB + 1 + DFF + 256) {
        // fragment-packed weights, octet layout [k>>3][n][k&7]
        int bb = b - (NZB + 1);
        if (bb < DFF) {
            int n = bb, k = t;   // w1[k][n]
            w1p[((size_t)(k >> 3) * 512 + n) * 8 + (k & 7)] = f2bf(w1[(size_t)k * DFF + n]);
        } else {
            int c = bb - DFF;    // w2[k2][c]
#pragma unroll
            for (int kk = 0; kk < 2; kk++) {
                int k2 = t + kk * 256;
                w2p[((size_t)(k2 >> 3) * 256 + c) * 8 + (k2 & 7)] = f2bf(w2[(size_t)k2 * 256 + c]);
            }
        }
    } else {
        // feat16 = bf16(sent @ W_src); el fused from register accumulators
        __shared__ float a[16][DIM];
        int rg = t >> 6;
        int lane = t & 63;
        int c0 = lane * 4;
        size_t row0 = (size_t)(b - (NZB + 1 + DFF + 256)) * 16;
#pragma unroll 4
        for (int i = 0; i < 16; i++) a[i][t] = sent[(row0 + i) * DIM + t];
        __syncthreads();
        float acc[4][4] = {};
        for (int kk = 0; kk < DIM; kk += 4) {
            float af[4][4];
#pragma unroll
            for (int i = 0; i < 4; i++) {
                float4 v = *(const float4*)&a[rg * 4 + i][kk];
                af[i][0] = v.x; af[i][1] = v.y; af[i][2] = v.z; af[i][3] = v.w;
            }
            float wf[4][4];
#pragma unroll
            for (int j2 = 0; j2 < 4; j2++) {
                float4 v = *(const float4*)&W_src[(size_t)(kk + j2) * DIM + c0];
                wf[j2][0] = v.x; wf[j2][1] = v.y; wf[j2][2] = v.z; wf[j2][3] = v.w;
            }
#pragma unroll
            for (int i = 0; i < 4; i++)
#pragma unroll
                for (int j2 = 0; j2 < 4; j2++)
#pragma unroll
                    for (int j = 0; j < 4; j++)
                        acc[i][j] = fmaf(af[i][j2], wf[j2][j], acc[i][j]);
        }
#pragma unroll
        for (int i = 0; i < 4; i++) {
            ushort4 p;
            p.x = f2bf(acc[i][0]); p.y = f2bf(acc[i][1]);
            p.z = f2bf(acc[i][2]); p.w = f2bf(acc[i][3]);
            *(ushort4*)&feat16[(row0 + rg * 4 + i) * DIM + c0] = p;
        }
        // el[n,h] = sum_d feat[n, h*64+d] * attn_l[h*64+d]; head = lane>>4
        int hh2 = lane >> 4;
        float4 alv = *(const float4*)(attn_l + c0);
#pragma unroll
        for (int i = 0; i < 4; i++) {
            float pel = acc[i][0] * alv.x + acc[i][1] * alv.y
                      + acc[i][2] * alv.z + acc[i][3] * alv.w;
#pragma unroll
            for (int m = 1; m < 16; m <<= 1) pel += __shfl_xor(pel, m, 64);
            if ((lane & 15) == 0)
                el[(row0 + rg * 4 + i) * NH + hh2] = pel;
        }
    }
}

// ---------------- scatter ----------------
__global__ void scatter_edges(const int* __restrict__ src, const int* __restrict__ dst,
                              int* __restrict__ count, unsigned short* __restrict__ bucket) {
    int e = blockIdx.x * 256 + threadIdx.x;
    if (e >= NE) return;
    int w = dst[e];
    int pos = atomicAdd(&count[w], 1);
    if (pos < CAP) bucket[(size_t)w * CAP + pos] = (unsigned short)src[e];
}

// ---------------- GAT: 2 nodes per wave, h -> bf16 ----------------
// hbf row n INTERLEAVED into d_out: bytes [1024n+512, 1024n+1024).
// Gather: r4 structure (low VGPR, high occupancy — TLP does the latency
// hiding; r5's 8-wide ILP unroll collapsed occupancy and regressed) plus a
// 1-deep prefetch.  All exp via native v_exp_f32 (__expf): scores bounded,
// ELU args <= 0, 1-ulp is plenty at bf16 output precision.
__global__ __launch_bounds__(256) void gat_h(
    const int* __restrict__ count, const unsigned short* __restrict__ bucket,
    const float* __restrict__ el, const float* __restrict__ Cdst,
    const unsigned short* __restrict__ feat16, const float* __restrict__ word,
    const float* __restrict__ gat_bias, unsigned short* hb)
{
    __shared__ unsigned short sbuf[8][64];
    __shared__ float abuf[8][4][64];
    int tid = threadIdx.x;
    int lane = tid & 63, wv = tid >> 6;
    int hl = lane & 31, half = lane >> 5;
    int nl = wv * 2 + half;                 // node-local 0..7
    int node = blockIdx.x * 8 + nl;
    int deg = count[node]; if (deg > CAP) deg = CAP;

    const float4* wr = (const float4*)(word + (size_t)node * DIM);
    float4 w0 = wr[hl * 2], w1v = wr[hl * 2 + 1];
    float wcol[8] = {w0.x, w0.y, w0.z, w0.w, w1v.x, w1v.y, w1v.z, w1v.w};

    // er inline: p[h] = sum_k word[k] * Cdst[k][h]
    const float4* Cv = (const float4*)Cdst;
    float p0 = 0.f, p1 = 0.f, p2 = 0.f, p3 = 0.f;
#pragma unroll
    for (int j = 0; j < 8; j++) {
        float4 c = Cv[hl * 8 + j];
        float wj = wcol[j];
        p0 = fmaf(wj, c.x, p0); p1 = fmaf(wj, c.y, p1);
        p2 = fmaf(wj, c.z, p2); p3 = fmaf(wj, c.w, p3);
    }
#pragma unroll
    for (int m = 1; m < 32; m <<= 1) {
        p0 += __shfl_xor(p0, m, 64); p1 += __shfl_xor(p1, m, 64);
        p2 += __shfl_xor(p2, m, 64); p3 += __shfl_xor(p3, m, 64);
    }

    // un-normalized exp scores for slots hl and hl+32 (scores bounded, no max)
    int sa = 0, sb = 0;
    float xa0 = 0.f, xa1 = 0.f, xa2 = 0.f, xa3 = 0.f;
    float xb0 = 0.f, xb1 = 0.f, xb2 = 0.f, xb3 = 0.f;
    if (hl < deg) {
        sa = bucket[(size_t)node * CAP + hl];
        float4 e = ((const float4*)el)[sa];
        float v;
        v = e.x + p0; xa0 = __expf(v > 0.f ? v : NEG_SLOPE * v);
        v = e.y + p1; xa1 = __expf(v > 0.f ? v : NEG_SLOPE * v);
        v = e.z + p2; xa2 = __expf(v > 0.f ? v : NEG_SLOPE * v);
        v = e.w + p3; xa3 = __expf(v > 0.f ? v : NEG_SLOPE * v);
    }
    if (hl + 32 < deg) {
        sb = bucket[(size_t)node * CAP + hl + 32];
        float4 e = ((const float4*)el)[sb];
        float v;
        v = e.x + p0; xb0 = __expf(v > 0.f ? v : NEG_SLOPE * v);
        v = e.y + p1; xb1 = __expf(v > 0.f ? v : NEG_SLOPE * v);
        v = e.z + p2; xb2 = __expf(v > 0.f ? v : NEG_SLOPE * v);
        v = e.w + p3; xb3 = __expf(v > 0.f ? v : NEG_SLOPE * v);
    }
    float d0 = xa0 + xb0, d1 = xa1 + xb1, d2 = xa2 + xb2, d3 = xa3 + xb3;
#pragma unroll
    for (int m = 1; m < 32; m <<= 1) {
        d0 += __shfl_xor(d0, m, 64); d1 += __shfl_xor(d1, m, 64);
        d2 += __shfl_xor(d2, m, 64); d3 += __shfl_xor(d3, m, 64);
    }
    float i0 = 1.f / d0, i1 = 1.f / d1, i2 = 1.f / d2, i3 = 1.f / d3;
    sbuf[nl][hl] = (unsigned short)sa;
    sbuf[nl][hl + 32] = (unsigned short)sb;
    abuf[nl][0][hl] = xa0 * i0; abuf[nl][0][hl + 32] = xb0 * i0;
    abuf[nl][1][hl] = xa1 * i1; abuf[nl][1][hl + 32] = xb1 * i1;
    abuf[nl][2][hl] = xa2 * i2; abuf[nl][2][hl + 32] = xb2 * i2;
    abuf[nl][3][hl] = xa3 * i3; abuf[nl][3][hl + 32] = xb3 * i3;
    __syncthreads();

    // gather: lane covers 8 cols, head hh = hl>>3; 1-deep prefetch
    int hh = hl >> 3;
    float acc[8] = {};
    const unsigned short* fcol = feat16 + hl * 8;
    if (deg > 0) {
        ushortx8 f = *(const ushortx8*)&fcol[(size_t)sbuf[nl][0] * DIM];
        for (int i = 0; i < deg; i++) {
            ushortx8 fn = f;
            if (i + 1 < deg)
                fn = *(const ushortx8*)&fcol[(size_t)sbuf[nl][i + 1] * DIM];
            float aa = abuf[nl][hh][i];
#pragma unroll
            for (int j = 0; j < 8; j++) acc[j] = fmaf(aa, bf2f(f[j]), acc[j]);
            f = fn;
        }
    }

    float4 g0 = ((const float4*)gat_bias)[hl * 2], g1 = ((const float4*)gat_bias)[hl * 2 + 1];
    float gb[8] = {g0.x, g0.y, g0.z, g0.w, g1.x, g1.y, g1.z, g1.w};
    ushortx8 o;
#pragma unroll
    for (int j = 0; j < 8; j++) {
        float r = acc[j] + gb[j];
        r = r > 0.f ? r : (__expf(r) - 1.f);
        o[j] = f2bf(wcol[j] + r);
    }
    *(ushortx8*)&hb[(size_t)node * 512 + 256 + hl * 8] = o;
}

// ---------------- Fused FFN v3: H in regs, weights LDS-double-buffered ----
// BM=256 rows, 512 threads (8 waves), each wave owns 32 rows x 256 out cols.
// H (32 rows x K=256) loaded ONCE to registers -> GEMM1's B operand free.
// Per 32-hid chunk: W1+W2 slices (32 KB) staged to LDS via global_load_lds,
// double-buffered one chunk ahead.  G1 swapped -> lane=row; bias/relu in regs;
// cvt_pk + permlane32_swap -> G2 A-frags in-register; G2 accumulates 256 cols.
__global__ __launch_bounds__(512, 2) void ffn_fused3(
    const unsigned short* hb,                // = (ushort*)d_out (aliases out!)
    const unsigned short* __restrict__ w1p,
    const float* __restrict__ b1,
    const unsigned short* __restrict__ w2p,
    const float* __restrict__ b2,
    float* out)
{
    __shared__ unsigned short W1s[2][8192];  // 16 KB each
    __shared__ unsigned short W2s[2][8192];
    int tid = threadIdx.x;
    int lane = tid & 63, wv = tid >> 6;
    int l31 = lane & 31, half = lane >> 5;
    int row0 = blockIdx.x * 256;

    int myrow = row0 + wv * 32 + l31;
    if (myrow >= NW) myrow = NW - 1;
    const unsigned short* hrow = hb + (size_t)myrow * 512 + 256 + half * 8;
    bf16x8 hreg[16];
#pragma unroll
    for (int ks = 0; ks < 16; ks++)
        hreg[ks] = *(const bf16x8*)(hrow + ks * 16);

    // stage chunk 0
    {
        if (wv < 4) {
#pragma unroll
            for (int it = 0; it < 4; it++) {
                int q = wv * 4 + it;
                const unsigned short* s =
                    w1p + ((size_t)(q * 2 + (lane >> 5)) * 512 + (lane & 31)) * 8;
                gload_lds16(s, &W1s[0][q * 512]);
            }
        } else {
#pragma unroll
            for (int it = 0; it < 4; it++) {
                int qq = (wv - 4) * 4 + it;
                const unsigned short* s = w2p + ((size_t)qq * 64 + lane) * 8;
                gload_lds16(s, &W2s[0][qq * 512]);
            }
        }
    }

    floatx16 oacc[8];
#pragma unroll
    for (int j = 0; j < 8; j++) oacc[j] = (floatx16)(0.f);
    __syncthreads();

#pragma unroll 2
    for (int hbi = 0; hbi < 16; hbi++) {
        int cur = hbi & 1;
        if (hbi < 15) {
            int c = hbi + 1, nb = cur ^ 1;
            if (wv < 4) {
#pragma unroll
                for (int it = 0; it < 4; it++) {
                    int q = wv * 4 + it;
                    const unsigned short* s =
                        w1p + ((size_t)(q * 2 + (lane >> 5)) * 512 + c * 32 + (lane & 31)) * 8;
                    gload_lds16(s, &W1s[nb][q * 512]);
                }
            } else {
#pragma unroll
                for (int it = 0; it < 4; it++) {
                    int qq = (wv - 4) * 4 + it;
                    const unsigned short* s = w2p + ((size_t)c * 1024 + qq * 64 + lane) * 8;
                    gload_lds16(s, &W2s[nb][qq * 512]);
                }
            }
        }
        const bf16x8* W1v = (const bf16x8*)W1s[cur];
        floatx16 hacc = (floatx16)(0.f);
#pragma unroll
        for (int ks = 0; ks < 16; ks++) {
            bf16x8 afrag = W1v[(ks * 2 + half) * 32 + l31];
            hacc = __builtin_amdgcn_mfma_f32_32x32x16_bf16(afrag, hreg[ks], hacc, 0, 0, 0);
        }
        const float* b1b = b1 + hbi * 32 + 4 * half;
        float4 bb0 = *(const float4*)(b1b + 0);
        float4 bb1 = *(const float4*)(b1b + 8);
        float4 bb2 = *(const float4*)(b1b + 16);
        float4 bb3 = *(const float4*)(b1b + 24);
        float bs[16] = {bb0.x, bb0.y, bb0.z, bb0.w, bb1.x, bb1.y, bb1.z, bb1.w,
                        bb2.x, bb2.y, bb2.z, bb2.w, bb3.x, bb3.y, bb3.z, bb3.w};
        float p[16];
#pragma unroll
        for (int j = 0; j < 16; j++) {
            float v = hacc[j] + bs[j];
            p[j] = v > 0.f ? v : 0.f;
        }
        unsigned int pk0 = cvt_pk_bf16(p[0], p[1]),   pk1 = cvt_pk_bf16(p[2], p[3]);
        unsigned int pk2 = cvt_pk_bf16(p[4], p[5]),   pk3 = cvt_pk_bf16(p[6], p[7]);
        unsigned int pk4 = cvt_pk_bf16(p[8], p[9]),   pk5 = cvt_pk_bf16(p[10], p[11]);
        unsigned int pk6 = cvt_pk_bf16(p[12], p[13]), pk7 = cvt_pk_bf16(p[14], p[15]);
        permlane32_swap(pk0, pk2);
        permlane32_swap(pk1, pk3);
        permlane32_swap(pk4, pk6);
        permlane32_swap(pk5, pk7);
        union { unsigned int u[4]; bf16x8 v; } f0, f1;
        f0.u[0] = pk0; f0.u[1] = pk1; f0.u[2] = pk2; f0.u[3] = pk3;  // hid 0..15
        f1.u[0] = pk4; f1.u[1] = pk5; f1.u[2] = pk6; f1.u[3] = pk7;  // hid 16..31
        const bf16x8* W2v = (const bf16x8*)W2s[cur];
#pragma unroll
        for (int ks2 = 0; ks2 < 2; ks2++) {
            bf16x8 pa = ks2 ? f1.v : f0.v;
#pragma unroll
            for (int ct = 0; ct < 8; ct++) {
                bf16x8 bfr = W2v[(ks2 * 2 + half) * 256 + ct * 32 + l31];
                oacc[ct] = __builtin_amdgcn_mfma_f32_32x32x16_bf16(pa, bfr, oacc[ct], 0, 0, 0);
            }
        }
        if (hbi < 15) __syncthreads();
    }
#pragma unroll
    for (int ct = 0; ct < 8; ct++) {
        int c = ct * 32 + l31;
        float bias = b2[c];
#pragma unroll
        for (int reg = 0; reg < 16; reg++) {
            int rloc = row0 + wv * 32 + (reg & 3) + 8 * (reg >> 2) + 4 * half;
            if (rloc < NW) out[(size_t)rloc * DIM + c] = oacc[ct][reg] + bias;
        }
    }
}

// ---------------- launch ----------------
extern "C" void kernel_launch(void* const* d_in, const int* in_sizes, int n_in,
                              void* d_out, int out_size, void* d_ws, size_t ws_size,
                              hipStream_t stream) {
    const float* word   = (const float*)d_in[0];
    const float* sent   = (const float*)d_in[1];
    const int*   src    = (const int*)d_in[2];
    const int*   dst    = (const int*)d_in[3];
    const float* W_src  = (const float*)d_in[4];
    const float* W_dst  = (const float*)d_in[5];
    const float* attn_l = (const float*)d_in[6];
    const float* attn_r = (const float*)d_in[7];
    const float* gbias  = (const float*)d_in[8];
    const float* w1     = (const float*)d_in[9];
    const float* b1     = (const float*)d_in[10];
    const float* w2     = (const float*)d_in[11];
    const float* b2     = (const float*)d_in[12];
    float* out = (float*)d_out;
    // hbf row n interleaved into d_out bytes [1024n+512, 1024n+1024)
    unsigned short* hb = (unsigned short*)d_out;

    char* wsb = (char*)d_ws;
    unsigned short* w1p = (unsigned short*)wsb;                 // 512*256
    unsigned short* w2p = w1p + (size_t)DFF * 256;              // 256*512
    float* el    = (float*)(w2p + (size_t)256 * DFF);           // NS*4
    float* C_dst = el + (size_t)NS * NH;                        // 256*4
    unsigned short* feat16 = (unsigned short*)(C_dst + DIM * NH);  // NS*256
    int* count = (int*)(feat16 + (size_t)NS * DIM);             // NW
    unsigned short* bucket = (unsigned short*)(count + NW);     // NW*CAP

    hipLaunchKernelGGL(prep_all, dim3(NZB + 1 + DFF + 256 + FG_B), dim3(256), 0, stream,
                       sent, W_src, attn_l, W_dst, attn_r, w1, w2,
                       C_dst, w1p, w2p, count, feat16, el);
    hipLaunchKernelGGL(scatter_edges, dim3(SC_B), dim3(256), 0, stream, src, dst, count, bucket);
    hipLaunchKernelGGL(gat_h, dim3(NW / 8), dim3(256), 0, stream,
                       count, bucket, el, C_dst, feat16, word, gbias, hb);
    hipLaunchKernelGGL(ffn_fused3, dim3(391), dim3(512), 0, stream,
                       hb, w1p, b1, w2p, b2, out);
}

// Round 7
// 436.394 us; speedup vs baseline: 1.0610x; 1.0054x over previous
//
#include <hip/hip_runtime.h>
#include <math.h>

#define NW 100000
#define NS 10000
#define NE 800000
#define DIM 256
#define NH 4
#define DFF 512
#define NEG_SLOPE 0.2f
#define CAP 64   // bucket capacity; deg ~ Poisson(8), P(>64) ~ 0

#define NZB 391          // ceil(NW/256) zero blocks
#define FG_B 625         // feat_gemm blocks (NS/16)
#define SC_B 3125        // scatter blocks (NE/256)

typedef __attribute__((ext_vector_type(8))) short bf16x8;
typedef __attribute__((ext_vector_type(8))) unsigned short ushortx8;
typedef __attribute__((ext_vector_type(16))) float floatx16;

// ---------------- helpers ----------------
__device__ __forceinline__ unsigned short f2bf(float f) {  // RNE fp32->bf16
    unsigned int u = __float_as_uint(f);
    unsigned int r = (u + 0x7fffu + ((u >> 16) & 1u)) >> 16;
    return (unsigned short)r;
}
__device__ __forceinline__ float bf2f(unsigned short u) {
    return __uint_as_float(((unsigned int)u) << 16);
}
__device__ __forceinline__ void gload_lds16(const void* g, void* l) {
    __builtin_amdgcn_global_load_lds(
        (const __attribute__((address_space(1))) unsigned int*)g,
        (__attribute__((address_space(3))) unsigned int*)l, 16, 0, 0);
}
// packs (lo,hi) -> [15:0]=bf16(lo), [31:16]=bf16(hi), RNE
__device__ __forceinline__ unsigned int cvt_pk_bf16(float lo, float hi) {
    unsigned int d;
    asm("v_cvt_pk_bf16_f32 %0, %1, %2" : "=v"(d) : "v"(lo), "v"(hi));
    return d;
}
// a'[i+32] = b[i]; b'[i] = a[i+32]
__device__ __forceinline__ void permlane32_swap(unsigned int& a, unsigned int& b) {
    asm("v_permlane32_swap_b32 %0, %1" : "+v"(a), "+v"(b));
}

// ---------------- merged prep kernel ----------------
// blocks: [0,391) zero_count | [391,392) compute_C (C_dst) |
//         [392,1160) prep_weights | [1160,1785) feat_gemm (+el fused).
__global__ __launch_bounds__(256) void prep_all(
    const float* __restrict__ sent, const float* __restrict__ W_src,
    const float* __restrict__ attn_l, const float* __restrict__ W_dst,
    const float* __restrict__ attn_r, const float* __restrict__ w1,
    const float* __restrict__ w2,
    float* __restrict__ C_dst,
    unsigned short* __restrict__ w1p, unsigned short* __restrict__ w2p,
    int* __restrict__ count, unsigned short* __restrict__ feat16,
    float* __restrict__ el)
{
    int b = blockIdx.x, t = threadIdx.x;
    if (b < NZB) {
        int i = b * 256 + t;
        if (i < NW) count[i] = 0;
    } else if (b < NZB + 1) {
        // C_dst[k,h] = sum_d W_dst[k, h*64+d] * attn_r[h,d]
        int k = t;
#pragma unroll
        for (int h = 0; h < NH; h++) {
            const float4* Wv = (const float4*)(W_dst + (size_t)k * DIM + h * 64);
            const float4* Av = (const float4*)(attn_r + h * 64);
            float s = 0.f;
#pragma unroll
            for (int d = 0; d < 16; d++) {
                float4 w = Wv[d], a = Av[d];
                s += w.x * a.x + w.y * a.y + w.z * a.z + w.w * a.w;
            }
            C_dst[k * NH + h] = s;
        }
    } else if (b < NZB + 1 + DFF + 256) {
        // fragment-packed weights, octet layout [k>>3][n][k&7]
        int bb = b - (NZB + 1);
        if (bb < DFF) {
            int n = bb, k = t;   // w1[k][n]
            w1p[((size_t)(k >> 3) * 512 + n) * 8 + (k & 7)] = f2bf(w1[(size_t)k * DFF + n]);
        } else {
            int c = bb - DFF;    // w2[k2][c]
#pragma unroll
            for (int kk = 0; kk < 2; kk++) {
                int k2 = t + kk * 256;
                w2p[((size_t)(k2 >> 3) * 256 + c) * 8 + (k2 & 7)] = f2bf(w2[(size_t)k2 * 256 + c]);
            }
        }
    } else {
        // feat16 = bf16(sent @ W_src); el fused from register accumulators
        __shared__ float a[16][DIM];
        int rg = t >> 6;
        int lane = t & 63;
        int c0 = lane * 4;
        size_t row0 = (size_t)(b - (NZB + 1 + DFF + 256)) * 16;
#pragma unroll 4
        for (int i = 0; i < 16; i++) a[i][t] = sent[(row0 + i) * DIM + t];
        __syncthreads();
        float acc[4][4] = {};
        for (int kk = 0; kk < DIM; kk += 4) {
            float af[4][4];
#pragma unroll
            for (int i = 0; i < 4; i++) {
                float4 v = *(const float4*)&a[rg * 4 + i][kk];
                af[i][0] = v.x; af[i][1] = v.y; af[i][2] = v.z; af[i][3] = v.w;
            }
            float wf[4][4];
#pragma unroll
            for (int j2 = 0; j2 < 4; j2++) {
                float4 v = *(const float4*)&W_src[(size_t)(kk + j2) * DIM + c0];
                wf[j2][0] = v.x; wf[j2][1] = v.y; wf[j2][2] = v.z; wf[j2][3] = v.w;
            }
#pragma unroll
            for (int i = 0; i < 4; i++)
#pragma unroll
                for (int j2 = 0; j2 < 4; j2++)
#pragma unroll
                    for (int j = 0; j < 4; j++)
                        acc[i][j] = fmaf(af[i][j2], wf[j2][j], acc[i][j]);
        }
#pragma unroll
        for (int i = 0; i < 4; i++) {
            ushort4 p;
            p.x = f2bf(acc[i][0]); p.y = f2bf(acc[i][1]);
            p.z = f2bf(acc[i][2]); p.w = f2bf(acc[i][3]);
            *(ushort4*)&feat16[(row0 + rg * 4 + i) * DIM + c0] = p;
        }
        // el[n,h] = sum_d feat[n, h*64+d] * attn_l[h*64+d]; head = lane>>4
        int hh2 = lane >> 4;
        float4 alv = *(const float4*)(attn_l + c0);
#pragma unroll
        for (int i = 0; i < 4; i++) {
            float pel = acc[i][0] * alv.x + acc[i][1] * alv.y
                      + acc[i][2] * alv.z + acc[i][3] * alv.w;
#pragma unroll
            for (int m = 1; m < 16; m <<= 1) pel += __shfl_xor(pel, m, 64);
            if ((lane & 15) == 0)
                el[(row0 + rg * 4 + i) * NH + hh2] = pel;
        }
    }
}

// ---------------- scatter ----------------
__global__ void scatter_edges(const int* __restrict__ src, const int* __restrict__ dst,
                              int* __restrict__ count, unsigned short* __restrict__ bucket) {
    int e = blockIdx.x * 256 + threadIdx.x;
    if (e >= NE) return;
    int w = dst[e];
    int pos = atomicAdd(&count[w], 1);
    if (pos < CAP) bucket[(size_t)w * CAP + pos] = (unsigned short)src[e];
}

// ---------------- GAT v2: ONE node per wave, async-staged gather ----------
// Latency-overlap structure (r6 was chain-serial):
//  * all independent loads (count, bucket, word) issue at t=0, masking late;
//    speculative indices clamped to NS-1 so el/feat reads stay in-bounds.
//  * as soon as bucket lands, first 8 feat rows are staged to LDS via paired
//    global_load_lds (lanes 0-31 = slot 2j, 32-63 = slot 2j+1) -- they fly
//    DURING the er/softmax phase instead of after it (T14).
//  * softmax: slot = lane (deg<=64), no half-split, no __syncthreads anywhere.
//  * gather: slots <8 from LDS; rare tail (deg>8) from global.
// LDS 20 KB/block exactly -> 8 blocks/CU, 32 waves resident.
__global__ __launch_bounds__(256) void gat_h(
    const int* __restrict__ count, const unsigned short* __restrict__ bucket,
    const float* __restrict__ el, const float* __restrict__ Cdst,
    const unsigned short* __restrict__ feat16, const float* __restrict__ word,
    const float* __restrict__ gat_bias, unsigned short* hb)
{
    __shared__ unsigned short Fs[4][8][256];  // staged feat rows, 16 KB
    __shared__ float abuf[4][64][4];          // alpha[slot][head], 4 KB
    int tid = threadIdx.x;
    int lane = tid & 63, wv = tid >> 6;
    int node = blockIdx.x * 4 + wv;

    // ---- speculative early issues ----
    int deg = count[node];
    int sraw = bucket[(size_t)node * CAP + lane];
    float4 wrow = *(const float4*)(word + (size_t)node * DIM + lane * 4);
    int s = sraw < NS ? sraw : NS - 1;
    float4 el4 = *(const float4*)(el + (size_t)s * 4);

    // ---- stage first 8 feat rows to LDS (issues overlap softmax below) ----
#pragma unroll
    for (int j = 0; j < 4; j++) {
        int sA = __shfl(s, 2 * j, 64);
        int sB = __shfl(s, 2 * j + 1, 64);
        int srow = (lane < 32) ? sA : sB;
        gload_lds16(feat16 + (size_t)srow * DIM + (lane & 31) * 8, &Fs[wv][2 * j][0]);
    }

    // ---- er[h] = sum_c word[c] * Cdst[c][h], reduced over 64 lanes ----
    const float4* Cv = (const float4*)Cdst;
    float p0 = 0.f, p1 = 0.f, p2 = 0.f, p3 = 0.f;
    {
        float wc[4] = {wrow.x, wrow.y, wrow.z, wrow.w};
#pragma unroll
        for (int j = 0; j < 4; j++) {
            float4 ch = Cv[lane * 4 + j];
            p0 = fmaf(wc[j], ch.x, p0); p1 = fmaf(wc[j], ch.y, p1);
            p2 = fmaf(wc[j], ch.z, p2); p3 = fmaf(wc[j], ch.w, p3);
        }
    }
#pragma unroll
    for (int m = 1; m < 64; m <<= 1) {
        p0 += __shfl_xor(p0, m, 64); p1 += __shfl_xor(p1, m, 64);
        p2 += __shfl_xor(p2, m, 64); p3 += __shfl_xor(p3, m, 64);
    }

    // ---- scores: slot = lane; exp directly (bounded, no max pass) ----
    int dg = deg > CAP ? CAP : deg;
    float x0 = 0.f, x1 = 0.f, x2 = 0.f, x3 = 0.f;
    if (lane < dg) {
        float v;
        v = el4.x + p0; x0 = __expf(v > 0.f ? v : NEG_SLOPE * v);
        v = el4.y + p1; x1 = __expf(v > 0.f ? v : NEG_SLOPE * v);
        v = el4.z + p2; x2 = __expf(v > 0.f ? v : NEG_SLOPE * v);
        v = el4.w + p3; x3 = __expf(v > 0.f ? v : NEG_SLOPE * v);
    }
    float d0 = x0, d1 = x1, d2 = x2, d3 = x3;
#pragma unroll
    for (int m = 1; m < 64; m <<= 1) {
        d0 += __shfl_xor(d0, m, 64); d1 += __shfl_xor(d1, m, 64);
        d2 += __shfl_xor(d2, m, 64); d3 += __shfl_xor(d3, m, 64);
    }
    float4 av;
    av.x = x0 * (1.f / d0); av.y = x1 * (1.f / d1);
    av.z = x2 * (1.f / d2); av.w = x3 * (1.f / d3);
    *(float4*)&abuf[wv][lane][0] = av;   // NaN if dg==0, never read

    // ---- gather: 4 cols per lane; staged slots from LDS, tail from global ----
    int hh = lane >> 4;
    float a0 = 0.f, a1 = 0.f, a2 = 0.f, a3 = 0.f;
    asm volatile("s_waitcnt vmcnt(0)" ::: "memory");  // staged rows landed
    int nst = dg < 8 ? dg : 8;
    for (int i = 0; i < nst; i++) {
        float aa = abuf[wv][i][hh];
        ushort4 f = *(const ushort4*)&Fs[wv][i][lane * 4];
        a0 = fmaf(aa, bf2f(f.x), a0); a1 = fmaf(aa, bf2f(f.y), a1);
        a2 = fmaf(aa, bf2f(f.z), a2); a3 = fmaf(aa, bf2f(f.w), a3);
    }
    for (int i = 8; i < dg; i++) {
        int si = __shfl(s, i, 64);
        float aa = abuf[wv][i][hh];
        ushort4 f = *(const ushort4*)&feat16[(size_t)si * DIM + lane * 4];
        a0 = fmaf(aa, bf2f(f.x), a0); a1 = fmaf(aa, bf2f(f.y), a1);
        a2 = fmaf(aa, bf2f(f.z), a2); a3 = fmaf(aa, bf2f(f.w), a3);
    }

    // ---- epilogue: +bias, ELU, +residual, bf16 store (8B/lane, 512B/wave) ----
    float4 gb = *(const float4*)(gat_bias + lane * 4);
    float r0 = a0 + gb.x, r1 = a1 + gb.y, r2 = a2 + gb.z, r3 = a3 + gb.w;
    r0 = r0 > 0.f ? r0 : (__expf(r0) - 1.f);
    r1 = r1 > 0.f ? r1 : (__expf(r1) - 1.f);
    r2 = r2 > 0.f ? r2 : (__expf(r2) - 1.f);
    r3 = r3 > 0.f ? r3 : (__expf(r3) - 1.f);
    unsigned int lo = cvt_pk_bf16(wrow.x + r0, wrow.y + r1);
    unsigned int hi = cvt_pk_bf16(wrow.z + r2, wrow.w + r3);
    uint2 o; o.x = lo; o.y = hi;
    *(uint2*)&hb[(size_t)node * 512 + 256 + lane * 4] = o;
}

// ---------------- Fused FFN v3: H in regs, weights LDS-double-buffered ----
// BM=256 rows, 512 threads (8 waves), each wave owns 32 rows x 256 out cols.
// H (32 rows x K=256) loaded ONCE to registers -> GEMM1's B operand free.
// Per 32-hid chunk: W1+W2 slices (32 KB) staged to LDS via global_load_lds,
// double-buffered one chunk ahead.  G1 swapped -> lane=row; bias/relu in regs;
// cvt_pk + permlane32_swap -> G2 A-frags in-register; G2 accumulates 256 cols.
__global__ __launch_bounds__(512, 2) void ffn_fused3(
    const unsigned short* hb,                // = (ushort*)d_out (aliases out!)
    const unsigned short* __restrict__ w1p,
    const float* __restrict__ b1,
    const unsigned short* __restrict__ w2p,
    const float* __restrict__ b2,
    float* out)
{
    __shared__ unsigned short W1s[2][8192];  // 16 KB each
    __shared__ unsigned short W2s[2][8192];
    int tid = threadIdx.x;
    int lane = tid & 63, wv = tid >> 6;
    int l31 = lane & 31, half = lane >> 5;
    int row0 = blockIdx.x * 256;

    int myrow = row0 + wv * 32 + l31;
    if (myrow >= NW) myrow = NW - 1;
    const unsigned short* hrow = hb + (size_t)myrow * 512 + 256 + half * 8;
    bf16x8 hreg[16];
#pragma unroll
    for (int ks = 0; ks < 16; ks++)
        hreg[ks] = *(const bf16x8*)(hrow + ks * 16);

    // stage chunk 0
    {
        if (wv < 4) {
#pragma unroll
            for (int it = 0; it < 4; it++) {
                int q = wv * 4 + it;
                const unsigned short* s =
                    w1p + ((size_t)(q * 2 + (lane >> 5)) * 512 + (lane & 31)) * 8;
                gload_lds16(s, &W1s[0][q * 512]);
            }
        } else {
#pragma unroll
            for (int it = 0; it < 4; it++) {
                int qq = (wv - 4) * 4 + it;
                const unsigned short* s = w2p + ((size_t)qq * 64 + lane) * 8;
                gload_lds16(s, &W2s[0][qq * 512]);
            }
        }
    }

    floatx16 oacc[8];
#pragma unroll
    for (int j = 0; j < 8; j++) oacc[j] = (floatx16)(0.f);
    __syncthreads();

#pragma unroll 2
    for (int hbi = 0; hbi < 16; hbi++) {
        int cur = hbi & 1;
        if (hbi < 15) {
            int c = hbi + 1, nb = cur ^ 1;
            if (wv < 4) {
#pragma unroll
                for (int it = 0; it < 4; it++) {
                    int q = wv * 4 + it;
                    const unsigned short* s =
                        w1p + ((size_t)(q * 2 + (lane >> 5)) * 512 + c * 32 + (lane & 31)) * 8;
                    gload_lds16(s, &W1s[nb][q * 512]);
                }
            } else {
#pragma unroll
                for (int it = 0; it < 4; it++) {
                    int qq = (wv - 4) * 4 + it;
                    const unsigned short* s = w2p + ((size_t)c * 1024 + qq * 64 + lane) * 8;
                    gload_lds16(s, &W2s[nb][qq * 512]);
                }
            }
        }
        const bf16x8* W1v = (const bf16x8*)W1s[cur];
        floatx16 hacc = (floatx16)(0.f);
#pragma unroll
        for (int ks = 0; ks < 16; ks++) {
            bf16x8 afrag = W1v[(ks * 2 + half) * 32 + l31];
            hacc = __builtin_amdgcn_mfma_f32_32x32x16_bf16(afrag, hreg[ks], hacc, 0, 0, 0);
        }
        const float* b1b = b1 + hbi * 32 + 4 * half;
        float4 bb0 = *(const float4*)(b1b + 0);
        float4 bb1 = *(const float4*)(b1b + 8);
        float4 bb2 = *(const float4*)(b1b + 16);
        float4 bb3 = *(const float4*)(b1b + 24);
        float bs[16] = {bb0.x, bb0.y, bb0.z, bb0.w, bb1.x, bb1.y, bb1.z, bb1.w,
                        bb2.x, bb2.y, bb2.z, bb2.w, bb3.x, bb3.y, bb3.z, bb3.w};
        float p[16];
#pragma unroll
        for (int j = 0; j < 16; j++) {
            float v = hacc[j] + bs[j];
            p[j] = v > 0.f ? v : 0.f;
        }
        unsigned int pk0 = cvt_pk_bf16(p[0], p[1]),   pk1 = cvt_pk_bf16(p[2], p[3]);
        unsigned int pk2 = cvt_pk_bf16(p[4], p[5]),   pk3 = cvt_pk_bf16(p[6], p[7]);
        unsigned int pk4 = cvt_pk_bf16(p[8], p[9]),   pk5 = cvt_pk_bf16(p[10], p[11]);
        unsigned int pk6 = cvt_pk_bf16(p[12], p[13]), pk7 = cvt_pk_bf16(p[14], p[15]);
        permlane32_swap(pk0, pk2);
        permlane32_swap(pk1, pk3);
        permlane32_swap(pk4, pk6);
        permlane32_swap(pk5, pk7);
        union { unsigned int u[4]; bf16x8 v; } f0, f1;
        f0.u[0] = pk0; f0.u[1] = pk1; f0.u[2] = pk2; f0.u[3] = pk3;  // hid 0..15
        f1.u[0] = pk4; f1.u[1] = pk5; f1.u[2] = pk6; f1.u[3] = pk7;  // hid 16..31
        const bf16x8* W2v = (const bf16x8*)W2s[cur];
#pragma unroll
        for (int ks2 = 0; ks2 < 2; ks2++) {
            bf16x8 pa = ks2 ? f1.v : f0.v;
#pragma unroll
            for (int ct = 0; ct < 8; ct++) {
                bf16x8 bfr = W2v[(ks2 * 2 + half) * 256 + ct * 32 + l31];
                oacc[ct] = __builtin_amdgcn_mfma_f32_32x32x16_bf16(pa, bfr, oacc[ct], 0, 0, 0);
            }
        }
        if (hbi < 15) __syncthreads();
    }
#pragma unroll
    for (int ct = 0; ct < 8; ct++) {
        int c = ct * 32 + l31;
        float bias = b2[c];
#pragma unroll
        for (int reg = 0; reg < 16; reg++) {
            int rloc = row0 + wv * 32 + (reg & 3) + 8 * (reg >> 2) + 4 * half;
            if (rloc < NW) out[(size_t)rloc * DIM + c] = oacc[ct][reg] + bias;
        }
    }
}

// ---------------- launch ----------------
extern "C" void kernel_launch(void* const* d_in, const int* in_sizes, int n_in,
                              void* d_out, int out_size, void* d_ws, size_t ws_size,
                              hipStream_t stream) {
    const float* word   = (const float*)d_in[0];
    const float* sent   = (const float*)d_in[1];
    const int*   src    = (const int*)d_in[2];
    const int*   dst    = (const int*)d_in[3];
    const float* W_src  = (const float*)d_in[4];
    const float* W_dst  = (const float*)d_in[5];
    const float* attn_l = (const float*)d_in[6];
    const float* attn_r = (const float*)d_in[7];
    const float* gbias  = (const float*)d_in[8];
    const float* w1     = (const float*)d_in[9];
    const float* b1     = (const float*)d_in[10];
    const float* w2     = (const float*)d_in[11];
    const float* b2     = (const float*)d_in[12];
    float* out = (float*)d_out;
    // hbf row n interleaved into d_out bytes [1024n+512, 1024n+1024)
    unsigned short* hb = (unsigned short*)d_out;

    char* wsb = (char*)d_ws;
    unsigned short* w1p = (unsigned short*)wsb;                 // 512*256
    unsigned short* w2p = w1p + (size_t)DFF * 256;              // 256*512
    float* el    = (float*)(w2p + (size_t)256 * DFF);           // NS*4
    float* C_dst = el + (size_t)NS * NH;                        // 256*4
    unsigned short* feat16 = (unsigned short*)(C_dst + DIM * NH);  // NS*256
    int* count = (int*)(feat16 + (size_t)NS * DIM);             // NW
    unsigned short* bucket = (unsigned short*)(count + NW);     // NW*CAP

    hipLaunchKernelGGL(prep_all, dim3(NZB + 1 + DFF + 256 + FG_B), dim3(256), 0, stream,
                       sent, W_src, attn_l, W_dst, attn_r, w1, w2,
                       C_dst, w1p, w2p, count, feat16, el);
    hipLaunchKernelGGL(scatter_edges, dim3(SC_B), dim3(256), 0, stream, src, dst, count, bucket);
    hipLaunchKernelGGL(gat_h, dim3(NW / 4), dim3(256), 0, stream,
                       count, bucket, el, C_dst, feat16, word, gbias, hb);
    hipLaunchKernelGGL(ffn_fused3, dim3(391), dim3(512), 0, stream,
                       hb, w1p, b1, w2p, b2, out);
}

// Round 8
// 432.097 us; speedup vs baseline: 1.0716x; 1.0099x over previous
//
#include <hip/hip_runtime.h>
#include <math.h>

#define NW 100000
#define NS 10000
#define NE 800000
#define DIM 256
#define NH 4
#define DFF 512
#define NEG_SLOPE 0.2f
#define CAP 64   // bucket capacity; deg ~ Poisson(8), P(>64) ~ 0

#define SC_B 3125        // scatter blocks (NE/256)

typedef __attribute__((ext_vector_type(8))) short bf16x8;
typedef __attribute__((ext_vector_type(8))) unsigned short ushortx8;
typedef __attribute__((ext_vector_type(16))) float floatx16;
typedef __attribute__((ext_vector_type(4))) float floatx4;

// ---------------- helpers ----------------
__device__ __forceinline__ unsigned short f2bf(float f) {  // RNE fp32->bf16
    unsigned int u = __float_as_uint(f);
    unsigned int r = (u + 0x7fffu + ((u >> 16) & 1u)) >> 16;
    return (unsigned short)r;
}
__device__ __forceinline__ float bf2f(unsigned short u) {
    return __uint_as_float(((unsigned int)u) << 16);
}
__device__ __forceinline__ void gload_lds16(const void* g, void* l) {
    __builtin_amdgcn_global_load_lds(
        (const __attribute__((address_space(1))) unsigned int*)g,
        (__attribute__((address_space(3))) unsigned int*)l, 16, 0, 0);
}
// packs (lo,hi) -> [15:0]=bf16(lo), [31:16]=bf16(hi), RNE
__device__ __forceinline__ unsigned int cvt_pk_bf16(float lo, float hi) {
    unsigned int d;
    asm("v_cvt_pk_bf16_f32 %0, %1, %2" : "=v"(d) : "v"(lo), "v"(hi));
    return d;
}
// a'[i+32] = b[i]; b'[i] = a[i+32]
__device__ __forceinline__ void permlane32_swap(unsigned int& a, unsigned int& b) {
    asm("v_permlane32_swap_b32 %0, %1" : "+v"(a), "+v"(b));
}

// ---------------- prep: C_dst, fragment-packed weights ----------------
// blocks: [0,1) compute_C | [1,769) w1p/w2p | [769,1025) wsp (W_src bf16 octets)
__global__ __launch_bounds__(256) void prep_all(
    const float* __restrict__ W_src, const float* __restrict__ W_dst,
    const float* __restrict__ attn_r, const float* __restrict__ w1,
    const float* __restrict__ w2,
    float* __restrict__ C_dst,
    unsigned short* __restrict__ w1p, unsigned short* __restrict__ w2p,
    unsigned short* __restrict__ wsp)
{
    int b = blockIdx.x, t = threadIdx.x;
    if (b < 1) {
        // C_dst[k,h] = sum_d W_dst[k, h*64+d] * attn_r[h,d]
        int k = t;
#pragma unroll
        for (int h = 0; h < NH; h++) {
            const float4* Wv = (const float4*)(W_dst + (size_t)k * DIM + h * 64);
            const float4* Av = (const float4*)(attn_r + h * 64);
            float s = 0.f;
#pragma unroll
            for (int d = 0; d < 16; d++) {
                float4 w = Wv[d], a = Av[d];
                s += w.x * a.x + w.y * a.y + w.z * a.z + w.w * a.w;
            }
            C_dst[k * NH + h] = s;
        }
    } else if (b < 1 + DFF + 256) {
        // fragment-packed FFN weights, octet layout [k>>3][n][k&7]
        int bb = b - 1;
        if (bb < DFF) {
            int n = bb, k = t;   // w1[k][n]
            w1p[((size_t)(k >> 3) * 512 + n) * 8 + (k & 7)] = f2bf(w1[(size_t)k * DFF + n]);
        } else {
            int c = bb - DFF;    // w2[k2][c]
#pragma unroll
            for (int kk = 0; kk < 2; kk++) {
                int k2 = t + kk * 256;
                w2p[((size_t)(k2 >> 3) * 256 + c) * 8 + (k2 & 7)] = f2bf(w2[(size_t)k2 * 256 + c]);
            }
        }
    } else {
        // wsp: W_src bf16 octet layout [k>>3][c][k&7]
        int c = b - (1 + DFF + 256);
        int k = t;
        wsp[((size_t)(k >> 3) * 256 + c) * 8 + (k & 7)] = f2bf(W_src[(size_t)k * DIM + c]);
    }
}

// ---------------- feat16 = bf16(sent @ W_src) via MFMA, el fused ----------
// block = 16 rows x 256 cols, 4 waves; wave wv covers cols wv*64.. (= head wv).
// A staged to LDS in octet layout (bank-clean); B frags straight from wsp (L2).
// el[n,h] = sum_c feat[n,c]*attn_l[c] over head h's 64 cols, reduced over the
// 16 lanes sharing a row via DPP-cheap xor masks 1/2/4/8.
__global__ __launch_bounds__(256) void feat_el(
    const float* __restrict__ sent, const unsigned short* __restrict__ wsp,
    const float* __restrict__ attn_l,
    unsigned short* __restrict__ feat16, float* __restrict__ el)
{
    __shared__ unsigned short As[32][16][8];   // [k>>3][row][k&7], 8 KB
    int t = threadIdx.x;
    int lane = t & 63, wv = t >> 6;
    int l15 = lane & 15, l4 = lane >> 4;
    size_t row0 = (size_t)blockIdx.x * 16;

    // stage A: thread t -> row t&15, col-group t>>4 (16 cols), bf16-converted
    {
        int r = t & 15, cg = t >> 4;
        const float* srow = sent + (row0 + r) * DIM + cg * 16;
        float4 v0 = *(const float4*)(srow + 0);
        float4 v1 = *(const float4*)(srow + 4);
        float4 v2 = *(const float4*)(srow + 8);
        float4 v3 = *(const float4*)(srow + 12);
        union { unsigned int u[4]; ushortx8 v; } p0, p1;
        p0.u[0] = cvt_pk_bf16(v0.x, v0.y); p0.u[1] = cvt_pk_bf16(v0.z, v0.w);
        p0.u[2] = cvt_pk_bf16(v1.x, v1.y); p0.u[3] = cvt_pk_bf16(v1.z, v1.w);
        p1.u[0] = cvt_pk_bf16(v2.x, v2.y); p1.u[1] = cvt_pk_bf16(v2.z, v2.w);
        p1.u[2] = cvt_pk_bf16(v3.x, v3.y); p1.u[3] = cvt_pk_bf16(v3.z, v3.w);
        *(ushortx8*)&As[cg * 2][r][0] = p0.v;
        *(ushortx8*)&As[cg * 2 + 1][r][0] = p1.v;
    }
    __syncthreads();

    floatx4 acc[4];
#pragma unroll
    for (int nt = 0; nt < 4; nt++) acc[nt] = (floatx4)(0.f);
    const bf16x8* wv8 = (const bf16x8*)wsp;
#pragma unroll
    for (int step = 0; step < 8; step++) {
        bf16x8 a = *(const bf16x8*)&As[l4 + step * 4][l15][0];
#pragma unroll
        for (int nt = 0; nt < 4; nt++) {
            int c = wv * 64 + nt * 16 + l15;
            bf16x8 bfr = wv8[(size_t)(l4 + step * 4) * 256 + c];
            acc[nt] = __builtin_amdgcn_mfma_f32_16x16x32_bf16(a, bfr, acc[nt], 0, 0, 0);
        }
    }
    // C layout: col = lane&15 (per n-tile), row = (lane>>4)*4 + reg
    float ep[4] = {0.f, 0.f, 0.f, 0.f};
#pragma unroll
    for (int nt = 0; nt < 4; nt++) {
        int c = wv * 64 + nt * 16 + l15;
        float al = attn_l[c];
#pragma unroll
        for (int r = 0; r < 4; r++) {
            int row = (int)row0 + l4 * 4 + r;
            feat16[(size_t)row * DIM + c] = f2bf(acc[nt][r]);
            ep[r] = fmaf(acc[nt][r], al, ep[r]);
        }
    }
#pragma unroll
    for (int m = 1; m < 16; m <<= 1) {
#pragma unroll
        for (int r = 0; r < 4; r++) ep[r] += __shfl_xor(ep[r], m, 64);
    }
    if (l15 == 0) {
#pragma unroll
        for (int r = 0; r < 4; r++)
            el[((size_t)row0 + l4 * 4 + r) * NH + wv] = ep[r];
    }
}

// ---------------- scatter ----------------
__global__ void scatter_edges(const int* __restrict__ src, const int* __restrict__ dst,
                              int* __restrict__ count, unsigned short* __restrict__ bucket) {
    int e = blockIdx.x * 256 + threadIdx.x;
    if (e >= NE) return;
    int w = dst[e];
    int pos = atomicAdd(&count[w], 1);
    if (pos < CAP) bucket[(size_t)w * CAP + pos] = (unsigned short)src[e];
}

// ---------------- GAT v2: ONE node per wave, async-staged gather ----------
// (r7 structure, unchanged; launched as two half-grids so the top-5 profile
//  table surfaces the next-largest kernels.)
__global__ __launch_bounds__(256) void gat_h(
    const int* __restrict__ count, const unsigned short* __restrict__ bucket,
    const float* __restrict__ el, const float* __restrict__ Cdst,
    const unsigned short* __restrict__ feat16, const float* __restrict__ word,
    const float* __restrict__ gat_bias, unsigned short* hb, int node0)
{
    __shared__ unsigned short Fs[4][8][256];  // staged feat rows, 16 KB
    __shared__ float abuf[4][64][4];          // alpha[slot][head], 4 KB
    int tid = threadIdx.x;
    int lane = tid & 63, wv = tid >> 6;
    int node = node0 + blockIdx.x * 4 + wv;

    // ---- speculative early issues ----
    int deg = count[node];
    int sraw = bucket[(size_t)node * CAP + lane];
    float4 wrow = *(const float4*)(word + (size_t)node * DIM + lane * 4);
    int s = sraw < NS ? sraw : NS - 1;
    float4 el4 = *(const float4*)(el + (size_t)s * 4);

    // ---- stage first 8 feat rows to LDS (overlaps er/softmax below) ----
#pragma unroll
    for (int j = 0; j < 4; j++) {
        int sA = __shfl(s, 2 * j, 64);
        int sB = __shfl(s, 2 * j + 1, 64);
        int srow = (lane < 32) ? sA : sB;
        gload_lds16(feat16 + (size_t)srow * DIM + (lane & 31) * 8, &Fs[wv][2 * j][0]);
    }

    // ---- er[h] = sum_c word[c] * Cdst[c][h], reduced over 64 lanes ----
    const float4* Cv = (const float4*)Cdst;
    float p0 = 0.f, p1 = 0.f, p2 = 0.f, p3 = 0.f;
    {
        float wc[4] = {wrow.x, wrow.y, wrow.z, wrow.w};
#pragma unroll
        for (int j = 0; j < 4; j++) {
            float4 ch = Cv[lane * 4 + j];
            p0 = fmaf(wc[j], ch.x, p0); p1 = fmaf(wc[j], ch.y, p1);
            p2 = fmaf(wc[j], ch.z, p2); p3 = fmaf(wc[j], ch.w, p3);
        }
    }
#pragma unroll
    for (int m = 1; m < 64; m <<= 1) {
        p0 += __shfl_xor(p0, m, 64); p1 += __shfl_xor(p1, m, 64);
        p2 += __shfl_xor(p2, m, 64); p3 += __shfl_xor(p3, m, 64);
    }

    // ---- scores: slot = lane; exp directly (bounded, no max pass) ----
    int dg = deg > CAP ? CAP : deg;
    float x0 = 0.f, x1 = 0.f, x2 = 0.f, x3 = 0.f;
    if (lane < dg) {
        float v;
        v = el4.x + p0; x0 = __expf(v > 0.f ? v : NEG_SLOPE * v);
        v = el4.y + p1; x1 = __expf(v > 0.f ? v : NEG_SLOPE * v);
        v = el4.z + p2; x2 = __expf(v > 0.f ? v : NEG_SLOPE * v);
        v = el4.w + p3; x3 = __expf(v > 0.f ? v : NEG_SLOPE * v);
    }
    float d0 = x0, d1 = x1, d2 = x2, d3 = x3;
#pragma unroll
    for (int m = 1; m < 64; m <<= 1) {
        d0 += __shfl_xor(d0, m, 64); d1 += __shfl_xor(d1, m, 64);
        d2 += __shfl_xor(d2, m, 64); d3 += __shfl_xor(d3, m, 64);
    }
    float4 av;
    av.x = x0 * (1.f / d0); av.y = x1 * (1.f / d1);
    av.z = x2 * (1.f / d2); av.w = x3 * (1.f / d3);
    *(float4*)&abuf[wv][lane][0] = av;   // NaN if dg==0, never read

    // ---- gather: 4 cols per lane; staged slots from LDS, tail from global ----
    int hh = lane >> 4;
    float a0 = 0.f, a1 = 0.f, a2 = 0.f, a3 = 0.f;
    asm volatile("s_waitcnt vmcnt(0)" ::: "memory");  // staged rows landed
    int nst = dg < 8 ? dg : 8;
    for (int i = 0; i < nst; i++) {
        float aa = abuf[wv][i][hh];
        ushort4 f = *(const ushort4*)&Fs[wv][i][lane * 4];
        a0 = fmaf(aa, bf2f(f.x), a0); a1 = fmaf(aa, bf2f(f.y), a1);
        a2 = fmaf(aa, bf2f(f.z), a2); a3 = fmaf(aa, bf2f(f.w), a3);
    }
    for (int i = 8; i < dg; i++) {
        int si = __shfl(s, i, 64);
        float aa = abuf[wv][i][hh];
        ushort4 f = *(const ushort4*)&feat16[(size_t)si * DIM + lane * 4];
        a0 = fmaf(aa, bf2f(f.x), a0); a1 = fmaf(aa, bf2f(f.y), a1);
        a2 = fmaf(aa, bf2f(f.z), a2); a3 = fmaf(aa, bf2f(f.w), a3);
    }

    // ---- epilogue: +bias, ELU, +residual, bf16 store ----
    float4 gb = *(const float4*)(gat_bias + lane * 4);
    float r0 = a0 + gb.x, r1 = a1 + gb.y, r2 = a2 + gb.z, r3 = a3 + gb.w;
    r0 = r0 > 0.f ? r0 : (__expf(r0) - 1.f);
    r1 = r1 > 0.f ? r1 : (__expf(r1) - 1.f);
    r2 = r2 > 0.f ? r2 : (__expf(r2) - 1.f);
    r3 = r3 > 0.f ? r3 : (__expf(r3) - 1.f);
    unsigned int lo = cvt_pk_bf16(wrow.x + r0, wrow.y + r1);
    unsigned int hi = cvt_pk_bf16(wrow.z + r2, wrow.w + r3);
    uint2 o; o.x = lo; o.y = hi;
    *(uint2*)&hb[(size_t)node * 512 + 256 + lane * 4] = o;
}

// ---------------- Fused FFN v3: H in regs, weights LDS-double-buffered ----
__global__ __launch_bounds__(512, 2) void ffn_fused3(
    const unsigned short* hb,                // = (ushort*)d_out (aliases out!)
    const unsigned short* __restrict__ w1p,
    const float* __restrict__ b1,
    const unsigned short* __restrict__ w2p,
    const float* __restrict__ b2,
    float* out)
{
    __shared__ unsigned short W1s[2][8192];  // 16 KB each
    __shared__ unsigned short W2s[2][8192];
    int tid = threadIdx.x;
    int lane = tid & 63, wv = tid >> 6;
    int l31 = lane & 31, half = lane >> 5;
    int row0 = blockIdx.x * 256;

    int myrow = row0 + wv * 32 + l31;
    if (myrow >= NW) myrow = NW - 1;
    const unsigned short* hrow = hb + (size_t)myrow * 512 + 256 + half * 8;
    bf16x8 hreg[16];
#pragma unroll
    for (int ks = 0; ks < 16; ks++)
        hreg[ks] = *(const bf16x8*)(hrow + ks * 16);

    // stage chunk 0
    {
        if (wv < 4) {
#pragma unroll
            for (int it = 0; it < 4; it++) {
                int q = wv * 4 + it;
                const unsigned short* s =
                    w1p + ((size_t)(q * 2 + (lane >> 5)) * 512 + (lane & 31)) * 8;
                gload_lds16(s, &W1s[0][q * 512]);
            }
        } else {
#pragma unroll
            for (int it = 0; it < 4; it++) {
                int qq = (wv - 4) * 4 + it;
                const unsigned short* s = w2p + ((size_t)qq * 64 + lane) * 8;
                gload_lds16(s, &W2s[0][qq * 512]);
            }
        }
    }

    floatx16 oacc[8];
#pragma unroll
    for (int j = 0; j < 8; j++) oacc[j] = (floatx16)(0.f);
    __syncthreads();

#pragma unroll 2
    for (int hbi = 0; hbi < 16; hbi++) {
        int cur = hbi & 1;
        if (hbi < 15) {
            int c = hbi + 1, nb = cur ^ 1;
            if (wv < 4) {
#pragma unroll
                for (int it = 0; it < 4; it++) {
                    int q = wv * 4 + it;
                    const unsigned short* s =
                        w1p + ((size_t)(q * 2 + (lane >> 5)) * 512 + c * 32 + (lane & 31)) * 8;
                    gload_lds16(s, &W1s[nb][q * 512]);
                }
            } else {
#pragma unroll
                for (int it = 0; it < 4; it++) {
                    int qq = (wv - 4) * 4 + it;
                    const unsigned short* s = w2p + ((size_t)c * 1024 + qq * 64 + lane) * 8;
                    gload_lds16(s, &W2s[nb][qq * 512]);
                }
            }
        }
        const bf16x8* W1v = (const bf16x8*)W1s[cur];
        floatx16 hacc = (floatx16)(0.f);
#pragma unroll
        for (int ks = 0; ks < 16; ks++) {
            bf16x8 afrag = W1v[(ks * 2 + half) * 32 + l31];
            hacc = __builtin_amdgcn_mfma_f32_32x32x16_bf16(afrag, hreg[ks], hacc, 0, 0, 0);
        }
        const float* b1b = b1 + hbi * 32 + 4 * half;
        float4 bb0 = *(const float4*)(b1b + 0);
        float4 bb1 = *(const float4*)(b1b + 8);
        float4 bb2 = *(const float4*)(b1b + 16);
        float4 bb3 = *(const float4*)(b1b + 24);
        float bs[16] = {bb0.x, bb0.y, bb0.z, bb0.w, bb1.x, bb1.y, bb1.z, bb1.w,
                        bb2.x, bb2.y, bb2.z, bb2.w, bb3.x, bb3.y, bb3.z, bb3.w};
        float p[16];
#pragma unroll
        for (int j = 0; j < 16; j++) {
            float v = hacc[j] + bs[j];
            p[j] = v > 0.f ? v : 0.f;
        }
        unsigned int pk0 = cvt_pk_bf16(p[0], p[1]),   pk1 = cvt_pk_bf16(p[2], p[3]);
        unsigned int pk2 = cvt_pk_bf16(p[4], p[5]),   pk3 = cvt_pk_bf16(p[6], p[7]);
        unsigned int pk4 = cvt_pk_bf16(p[8], p[9]),   pk5 = cvt_pk_bf16(p[10], p[11]);
        unsigned int pk6 = cvt_pk_bf16(p[12], p[13]), pk7 = cvt_pk_bf16(p[14], p[15]);
        permlane32_swap(pk0, pk2);
        permlane32_swap(pk1, pk3);
        permlane32_swap(pk4, pk6);
        permlane32_swap(pk5, pk7);
        union { unsigned int u[4]; bf16x8 v; } f0, f1;
        f0.u[0] = pk0; f0.u[1] = pk1; f0.u[2] = pk2; f0.u[3] = pk3;  // hid 0..15
        f1.u[0] = pk4; f1.u[1] = pk5; f1.u[2] = pk6; f1.u[3] = pk7;  // hid 16..31
        const bf16x8* W2v = (const bf16x8*)W2s[cur];
#pragma unroll
        for (int ks2 = 0; ks2 < 2; ks2++) {
            bf16x8 pa = ks2 ? f1.v : f0.v;
#pragma unroll
            for (int ct = 0; ct < 8; ct++) {
                bf16x8 bfr = W2v[(ks2 * 2 + half) * 256 + ct * 32 + l31];
                oacc[ct] = __builtin_amdgcn_mfma_f32_32x32x16_bf16(pa, bfr, oacc[ct], 0, 0, 0);
            }
        }
        if (hbi < 15) __syncthreads();
    }
#pragma unroll
    for (int ct = 0; ct < 8; ct++) {
        int c = ct * 32 + l31;
        float bias = b2[c];
#pragma unroll
        for (int reg = 0; reg < 16; reg++) {
            int rloc = row0 + wv * 32 + (reg & 3) + 8 * (reg >> 2) + 4 * half;
            if (rloc < NW) out[(size_t)rloc * DIM + c] = oacc[ct][reg] + bias;
        }
    }
}

// ---------------- launch ----------------
extern "C" void kernel_launch(void* const* d_in, const int* in_sizes, int n_in,
                              void* d_out, int out_size, void* d_ws, size_t ws_size,
                              hipStream_t stream) {
    const float* word   = (const float*)d_in[0];
    const float* sent   = (const float*)d_in[1];
    const int*   src    = (const int*)d_in[2];
    const int*   dst    = (const int*)d_in[3];
    const float* W_src  = (const float*)d_in[4];
    const float* W_dst  = (const float*)d_in[5];
    const float* attn_l = (const float*)d_in[6];
    const float* attn_r = (const float*)d_in[7];
    const float* gbias  = (const float*)d_in[8];
    const float* w1     = (const float*)d_in[9];
    const float* b1     = (const float*)d_in[10];
    const float* w2     = (const float*)d_in[11];
    const float* b2     = (const float*)d_in[12];
    float* out = (float*)d_out;
    // hbf row n interleaved into d_out bytes [1024n+512, 1024n+1024)
    unsigned short* hb = (unsigned short*)d_out;

    char* wsb = (char*)d_ws;
    unsigned short* w1p = (unsigned short*)wsb;                 // 512*256
    unsigned short* w2p = w1p + (size_t)DFF * 256;              // 256*512
    unsigned short* wsp = w2p + (size_t)256 * DFF;              // 256*256
    float* el    = (float*)(wsp + (size_t)DIM * DIM);           // NS*4
    float* C_dst = el + (size_t)NS * NH;                        // 256*4
    unsigned short* feat16 = (unsigned short*)(C_dst + DIM * NH);  // NS*256
    int* count = (int*)(feat16 + (size_t)NS * DIM);             // NW
    unsigned short* bucket = (unsigned short*)(count + NW);     // NW*CAP

    hipMemsetAsync(count, 0, (size_t)NW * sizeof(int), stream);
    hipLaunchKernelGGL(scatter_edges, dim3(SC_B), dim3(256), 0, stream, src, dst, count, bucket);
    hipLaunchKernelGGL(prep_all, dim3(1 + DFF + 256 + 256), dim3(256), 0, stream,
                       W_src, W_dst, attn_r, w1, w2, C_dst, w1p, w2p, wsp);
    hipLaunchKernelGGL(feat_el, dim3(NS / 16), dim3(256), 0, stream,
                       sent, wsp, attn_l, feat16, el);
    hipLaunchKernelGGL(gat_h, dim3(NW / 8), dim3(256), 0, stream,
                       count, bucket, el, C_dst, feat16, word, gbias, hb, 0);
    hipLaunchKernelGGL(gat_h, dim3(NW / 8), dim3(256), 0, stream,
                       count, bucket, el, C_dst, feat16, word, gbias, hb, NW / 2);
    hipLaunchKernelGGL(ffn_fused3, dim3(391), dim3(512), 0, stream,
                       hb, w1p, b1, w2p, b2, out);
}